// Round 1
// baseline (76.207 us; speedup 1.0000x reference)
//
#include <hip/hip_runtime.h>

// Problem geometry (fixed by the reference).
#define OUT_FEATURES 8192
#define PACKED_COLS  4096          // IN_FEATURES / 2, one packed byte per int32
#define PCOLS_SHIFT  12            // log2(PACKED_COLS)

// Each thread: load 4 packed bytes (int4 = 16B), emit 8 floats (2x float4 = 32B).
__global__ void __launch_bounds__(256)
dequant_u4_kernel(const int* __restrict__ w,
                  const float* __restrict__ scale,
                  const float* __restrict__ zero_point,
                  float* __restrict__ out) {
    const int tid = blockIdx.x * blockDim.x + threadIdx.x;   // 0 .. 8192*4096/4 - 1
    const int packed_idx = tid << 2;                         // first packed col handled
    const int row = packed_idx >> PCOLS_SHIFT;
    const int col = packed_idx & (PACKED_COLS - 1);

    const float s = scale[row];
    const float b = -zero_point[row] * s;                    // out = n*s + b

    const int4 wv = *reinterpret_cast<const int4*>(w + packed_idx);

    float4 o0, o1;
    o0.x = fmaf((float)( wv.x       & 0xF), s, b);
    o0.y = fmaf((float)((wv.x >> 4) & 0xF), s, b);
    o0.z = fmaf((float)( wv.y       & 0xF), s, b);
    o0.w = fmaf((float)((wv.y >> 4) & 0xF), s, b);
    o1.x = fmaf((float)( wv.z       & 0xF), s, b);
    o1.y = fmaf((float)((wv.z >> 4) & 0xF), s, b);
    o1.z = fmaf((float)( wv.w       & 0xF), s, b);
    o1.w = fmaf((float)((wv.w >> 4) & 0xF), s, b);

    float* op = out + (size_t)row * (2 * PACKED_COLS) + 2 * col;
    *reinterpret_cast<float4*>(op)     = o0;
    *reinterpret_cast<float4*>(op + 4) = o1;
}

extern "C" void kernel_launch(void* const* d_in, const int* in_sizes, int n_in,
                              void* d_out, int out_size, void* d_ws, size_t ws_size,
                              hipStream_t stream) {
    const int*   w          = (const int*)d_in[0];
    const float* scale      = (const float*)d_in[1];
    const float* zero_point = (const float*)d_in[2];
    float*       out        = (float*)d_out;

    const int total_threads = OUT_FEATURES * PACKED_COLS / 4;  // 8,388,608
    const int block = 256;
    const int grid  = total_threads / block;                   // 32768, exact

    dequant_u4_kernel<<<grid, block, 0, stream>>>(w, scale, zero_point, out);
}